// Round 16
// baseline (458.649 us; speedup 1.0000x reference)
//
#include <hip/hip_runtime.h>
#include <hip/hip_cooperative_groups.h>

namespace cg = cooperative_groups;

#define Bn 32
#define Wn 128
#define Sn 192
#define Dn 768
#define Hn 10
#define BHn 30
#define Cn 50
#define NEGV -1e30f

typedef _Float16 h2 __attribute__((ext_vector_type(2)));
typedef _Float16 h8 __attribute__((ext_vector_type(8)));
typedef __fp16 fp16x2 __attribute__((ext_vector_type(2)));
union H8u { h8 v; h2 p[4]; float4 f; };

__device__ __forceinline__ float fsig(float x) {
    return __builtin_amdgcn_rcpf(1.0f + __expf(-x));
}
__device__ __forceinline__ float ftanh(float x) {
    return 1.0f - 2.0f * __builtin_amdgcn_rcpf(1.0f + __expf(2.0f * x));
}
__device__ __forceinline__ float lane_bcast(float v, int srclane) {
    union { float f; int i; } u, w;
    u.f = v;
    w.i = __builtin_amdgcn_readlane(u.i, srclane);
    return w.f;
}
template <int Q>
__device__ __forceinline__ float quad_bcast(float v) {
    union { float f; int i; } u, w;
    u.f = v;
    w.i = __builtin_amdgcn_mov_dpp(u.i, (Q << 6) | (Q << 4) | (Q << 2) | Q, 0xf, 0xf, true);
    return w.f;
}
__device__ __forceinline__ h2 pk16(float a, float b) {
#if __has_builtin(__builtin_amdgcn_cvt_pkrtz)
    union { fp16x2 r; h2 h; } u;
    u.r = __builtin_amdgcn_cvt_pkrtz(a, b);
    return u.h;
#else
    h2 r; r[0] = (_Float16)a; r[1] = (_Float16)b; return r;
#endif
}
__device__ __forceinline__ float dot2f(h2 a, h2 b, float c) {
#if __has_builtin(__builtin_amdgcn_fdot2)
    return __builtin_amdgcn_fdot2(a, b, c, false);
#else
    return c + (float)a[0] * (float)b[0] + (float)a[1] * (float)b[1];
#endif
}

struct MegaP {
    const float* hid;
    const int* b2t;
    const int* heads;
    const int* dep_rels;
    const unsigned char* masks;
    const float* Wih_f; const float* Whh_f; const float* bih_f; const float* bhh_f;
    const float* Wih_b; const float* Whh_b; const float* bih_b; const float* bhh_b;
    const float* un_W1; const float* un_b1; const float* un_W2; const float* un_b2;
    const float* un_U;  const float* un_bias;
    const float* dr_W1; const float* dr_b1; const float* dr_W2; const float* dr_b2;
    const float* dr_U;  const float* dr_bias;
    float* tokg4; float* xg; float* hs; float* hpad; float* sc; float* out;
};

// One cooperative kernel: A tokproj -> B wordmean -> C lstm -> D mlp -> E drscore -> F losses
__global__ __launch_bounds__(256) void k_mega(MegaP P) {
    __shared__ __align__(16) char smraw[29952]; // max phase need: (64+80)*52 h2 = 29952B
    cg::grid_group grid = cg::this_grid();
    int tid = threadIdx.x;
    int bid = blockIdx.x;

    // ================= Phase A: token projection (f16 LDS + v_dot2), 768 tiles =================
    if (bid == 0 && tid == 0) P.out[0] = 0.f;
    {
        h2* xl = (h2*)smraw;                  // 64 x 52
        h2* wl = (h2*)(smraw + 64 * 52 * 4);  // 80 x 52
        for (int tile = bid; tile < 768; tile += 512) {
            int tb = tile >> 3;
            int kq = tile & 7;
            int b = tb / 3;
            int s0 = (tb % 3) * 64;
            int k0 = kq * 96;
            for (int idx = tid; idx < 64 * 24; idx += 256) {
                int r = idx / 24, k4 = idx % 24;
                size_t rowbase = ((size_t)b * (Sn + 1) + (s0 + r + 1)) * Dn + k0 + 4 * k4;
                float4 v0 = *(const float4*)(P.hid + rowbase);
                float4 v1 = *(const float4*)(P.hid + (size_t)Bn * (Sn + 1) * Dn + rowbase);
                float4 v2 = *(const float4*)(P.hid + (size_t)2 * Bn * (Sn + 1) * Dn + rowbase);
                xl[r * 52 + 2 * k4] = pk16(v0.x + v1.x + v2.x, v0.y + v1.y + v2.y);
                xl[r * 52 + 2 * k4 + 1] = pk16(v0.z + v1.z + v2.z, v0.w + v1.w + v2.w);
            }
            for (int idx = tid; idx < 80 * 24; idx += 256) {
                int co = idx / 24, k4 = idx % 24;
                int dir = co / 40, off = co % 40;
                int j = off >> 2, g = off & 3;
                const float4 w = *(const float4*)((dir ? P.Wih_b : P.Wih_f) + (g * 10 + j) * Dn + k0 + 4 * k4);
                wl[co * 52 + 2 * k4] = pk16(w.x, w.y);
                wl[co * 52 + 2 * k4 + 1] = pk16(w.z, w.w);
            }
            __syncthreads();
            int tg_ = tid >> 4;
            int rg = tid & 15;
            float acc[4][5];
#pragma unroll
            for (int tt = 0; tt < 4; ++tt)
#pragma unroll
                for (int rr = 0; rr < 5; ++rr) acc[tt][rr] = 0.f;
            for (int kk = 0; kk < 12; ++kk) {
                H8u xv[4], wv[5];
#pragma unroll
                for (int tt = 0; tt < 4; ++tt)
                    xv[tt].v = *(const h8*)(xl + (tg_ * 4 + tt) * 52 + kk * 4);
#pragma unroll
                for (int rr = 0; rr < 5; ++rr)
                    wv[rr].v = *(const h8*)(wl + (rg * 5 + rr) * 52 + kk * 4);
#pragma unroll
                for (int tt = 0; tt < 4; ++tt)
#pragma unroll
                    for (int rr = 0; rr < 5; ++rr) {
                        float a = acc[tt][rr];
                        a = dot2f(xv[tt].p[0], wv[rr].p[0], a);
                        a = dot2f(xv[tt].p[1], wv[rr].p[1], a);
                        a = dot2f(xv[tt].p[2], wv[rr].p[2], a);
                        a = dot2f(xv[tt].p[3], wv[rr].p[3], a);
                        acc[tt][rr] = a;
                    }
            }
            size_t nbase = (size_t)kq * (Bn * Sn) + (size_t)b * Sn + s0;
#pragma unroll
            for (int tt = 0; tt < 4; ++tt) {
                size_t ob = (nbase + tg_ * 4 + tt) * 80 + rg * 5;
#pragma unroll
                for (int rr = 0; rr < 5; ++rr) P.tokg4[ob + rr] = acc[tt][rr];
            }
            __syncthreads();
        }
    }
    grid.sync();

    // ================= Phase B: word segment-mean (b2t scan) =================
    {
        int b = bid >> 4;
        int w0 = (bid & 15) * 8;
        int* ws = (int*)smraw;
        if (tid < 192) ws[tid] = P.b2t[b * Sn + tid];
        __syncthreads();
        if (tid < 80) {
            const size_t NT80 = (size_t)Bn * Sn * 80;
            int dir = tid / 40, off = tid % 40;
            int brow = (off & 3) * 10 + (off >> 2);
            float bias = (dir ? P.bih_b : P.bih_f)[brow];
            for (int ww = 0; ww < 8; ++ww) {
                int w = w0 + ww;
                float acc = 0.f;
                int cnt = 0;
                for (int s = 0; s < Sn; ++s) {
                    if (ws[s] == w) {
                        ++cnt;
                        size_t base = ((size_t)b * Sn + s) * 80 + tid;
#pragma unroll
                        for (int p = 0; p < 8; ++p) acc += P.tokg4[base + p * NT80];
                    }
                }
                float inv = 1.0f / (3.0f * (float)(cnt > 0 ? cnt : 1));
                P.xg[((size_t)(dir * Bn + b) * Wn + w) * 40 + off] = acc * inv + bias;
            }
        }
        __syncthreads();
    }
    grid.sync();

    // ================= Phase C: LSTM scan (blocks 0..63, wave 0) =================
    if (bid < 64 && tid < 64) {
        int lane = tid;
        int seq = bid;
        int dir = seq >> 5;
        int l = lane < 40 ? lane : 39;
        int j = l >> 2, G = l & 3;
        const float* Whh = dir ? P.Whh_b : P.Whh_f;
        const float* bhh = dir ? P.bhh_b : P.bhh_f;
        float wk[Hn];
#pragma unroll
        for (int k = 0; k < Hn; ++k) wk[k] = Whh[(G * Hn + j) * Hn + k];
        float bias = bhh[G * Hn + j];
        const float* xbase = P.xg + (size_t)seq * Wn * 40;
        float* hbase = P.hs + (size_t)seq * Wn * Hn;
        bool st = (G == 0) && (lane < 40);
        float h = 0.f, c = 0.f;
        int dt = dir ? -1 : 1;
        int t = dir ? (Wn - 1) : 0;
        float xq[8];
#pragma unroll
        for (int q = 0; q < 7; ++q) xq[q] = xbase[(t + q * dt) * 40 + l];
#pragma unroll 8
        for (int step = 0; step < Wn; ++step) {
            float xv = xq[step & 7];
            xq[(step + 7) & 7] = xbase[(t + 7 * dt) * 40 + l];
            float hb[Hn];
#pragma unroll
            for (int k = 0; k < Hn; ++k) hb[k] = lane_bcast(h, 4 * k);
            float ga = xv, gb = bias;
#pragma unroll
            for (int k = 0; k < 5; ++k) ga += wk[k] * hb[k];
#pragma unroll
            for (int k = 5; k < Hn; ++k) gb += wk[k] * hb[k];
            float g = ga + gb;
            float gin = (G == 2) ? 2.f * g : g;
            float s = fsig(gin);
            float av = (G == 2) ? 2.f * s - 1.f : s;
            float ai = quad_bcast<0>(av);
            float af = quad_bcast<1>(av);
            float ag = quad_bcast<2>(av);
            float ao = quad_bcast<3>(av);
            c = af * c + ai * ag;
            h = ao * ftanh(c);
            if (st) hbase[t * Hn + j] = h;
            t += dt;
        }
    }
    grid.sync();

    // ================= Phase D: MLP heads -> hpad (8 bt tiles per block) =================
    {
        int bt0 = bid * 8;
        float* xm = (float*)smraw; // [8][20]
        for (int idx = tid; idx < 160; idx += 256) {
            int tl = idx / 20, d = idx % 20;
            int bt = bt0 + tl;
            int b = bt >> 7, t = bt & 127;
            xm[idx] = (d < Hn) ? P.hs[((size_t)(0 * Bn + b) * Wn + t) * Hn + d]
                               : P.hs[((size_t)(1 * Bn + b) * Wn + t) * Hn + (d - Hn)];
        }
        __syncthreads();
#pragma unroll
        for (int p = 0; p < 4; ++p) {
            int idx = p * 256 + tid;      // 0..1023 = 8 tiles x 128 outputs
            int tl = idx >> 7, q = idx & 127;
            int which = q >> 5, k = q & 31;
            int bt = bt0 + tl;
            size_t obase = ((size_t)which * Bn * Wn + bt) * 32;
            if (k == 31) {
                P.hpad[obase + 31] = 0.f;
            } else if (k == 30) {
                P.hpad[obase + 30] = 1.0f;
            } else {
                const float* Wm;
                const float* bv;
                if (which == 0) { Wm = P.un_W1; bv = P.un_b1; }
                else if (which == 1) { Wm = P.un_W2; bv = P.un_b2; }
                else if (which == 2) { Wm = P.dr_W1; bv = P.dr_b1; }
                else { Wm = P.dr_W2; bv = P.dr_b2; }
                float a = bv[k];
#pragma unroll
                for (int d = 0; d < 20; ++d) a += xm[tl * 20 + d] * Wm[d * BHn + k];
                P.hpad[obase + k] = a > 0.f ? a : 0.f;
            }
        }
        __syncthreads();
    }
    grid.sync();

    // ================= Phase E: deprel scores (832 tiles, 2 iters) =================
    {
        float* Ul = (float*)smraw; // [4][992]
        for (int it = 0; it < 2; ++it) {
            int tile = bid + it * 512;
            bool valid = tile < 832;
            int nc = tile & 63;
            int oq = tile >> 6;
            if (valid) {
                for (int idx = tid; idx < 4 * 992; idx += 256) {
                    int o = idx / 992, r = idx - o * 992;
                    int h = r >> 5, g = r & 31;
                    int oo = oq * 4 + o; if (oo >= Cn) oo = Cn - 1;
                    Ul[o * 992 + r] = (g < 31) ? P.dr_U[(size_t)oo * 961 + h * 31 + g] : 0.f;
                }
            }
            int w = tid >> 6, lane = tid & 63;
            int o = oq * 4 + w;
            int n = nc * 64 + lane;
            float h2r[32], h1r[32];
            if (valid) {
                int b = n >> 7;
                int jh = P.heads[n];
                if (jh < 0 || jh >= Wn) jh = 0;
                const float4* p1 = (const float4*)(P.hpad + ((size_t)2 * Bn * Wn + n) * 32);
                const float4* p2 = (const float4*)(P.hpad + ((size_t)3 * Bn * Wn + b * Wn + jh) * 32);
#pragma unroll
                for (int q = 0; q < 8; ++q) {
                    float4 v2 = p2[q];
                    h2r[4 * q + 0] = v2.x; h2r[4 * q + 1] = v2.y;
                    h2r[4 * q + 2] = v2.z; h2r[4 * q + 3] = v2.w;
                    float4 v1 = p1[q];
                    h1r[4 * q + 0] = v1.x; h1r[4 * q + 1] = v1.y;
                    h1r[4 * q + 2] = v1.z; h1r[4 * q + 3] = v1.w;
                }
            }
            __syncthreads();
            if (valid) {
                const float* up = Ul + w * 992;
                float acc = 0.f;
                for (int h = 0; h < 31; ++h) {
                    float t = 0.f;
#pragma unroll
                    for (int g = 0; g < 32; ++g) t += up[h * 32 + g] * h2r[g];
                    acc += h1r[h] * t;
                }
                if (o < Cn) P.sc[(size_t)n * Cn + o] = acc + P.dr_bias[o];
            }
            __syncthreads();
        }
    }
    grid.sync();

    // ================= Phase F: fused losses (blocks 0..127) =================
    if (bid < 128) {
        int b = bid >> 2;
        int ic = bid & 3;
        float* h2s_ = (float*)smraw;        // 128*36
        float* tgf = h2s_ + 128 * 36;       // 32*36
        float* U0l = tgf + 32 * 36;         // 992
        float* redf = U0l + 992;            // 256
        const float* h1a = P.hpad + (size_t)b * Wn * 32;
        const float* h2a = P.hpad + ((size_t)Bn * Wn + b * Wn) * 32;
        for (int idx = tid; idx < 128 * 32; idx += 256)
            h2s_[(idx >> 5) * 36 + (idx & 31)] = h2a[idx];
        for (int idx = tid; idx < 992; idx += 256) {
            int g = idx & 31;
            U0l[idx] = (g < 31) ? P.un_U[(idx >> 5) * 31 + g] : 0.f;
        }
        __syncthreads();
        {
            int l = tid & 31, ig = tid >> 5;
            float ur[31];
#pragma unroll
            for (int h = 0; h < 31; ++h) ur[h] = U0l[h * 32 + l];
            for (int ii = 0; ii < 4; ++ii) {
                int il = ig * 4 + ii;
                int i = ic * 32 + il;
                const float4* hp = (const float4*)(h1a + (size_t)i * 32);
                float hr[32];
#pragma unroll
                for (int q = 0; q < 8; ++q) {
                    float4 v = hp[q];
                    hr[4 * q] = v.x; hr[4 * q + 1] = v.y; hr[4 * q + 2] = v.z; hr[4 * q + 3] = v.w;
                }
                float a = 0.f;
#pragma unroll
                for (int h = 0; h < 31; ++h) a += hr[h] * ur[h];
                tgf[il * 36 + l] = a;
            }
        }
        __syncthreads();
        float acc = 0.f;
        {
            int jg = tid & 7, il = tid >> 3;
            int i = ic * 32 + il;
            float ub = P.un_bias[0];
            float4 tq[8];
            const float4* tp = (const float4*)(tgf + il * 36);
#pragma unroll
            for (int q = 0; q < 8; ++q) tq[q] = tp[q];
            float m = -3e38f, lsum = 0.f, sh = 0.f;
            int hd = P.heads[b * Wn + i];
            for (int jj = 0; jj < 16; ++jj) {
                int j = jg * 16 + ((jj + jg) & 15);
                const float4* h2p = (const float4*)(h2s_ + j * 36);
                float s = ub;
#pragma unroll
                for (int q = 0; q < 8; ++q) {
                    float4 hq = h2p[q];
                    s += tq[q].x * hq.x + tq[q].y * hq.y + tq[q].z * hq.z + tq[q].w * hq.w;
                }
                if (j == i) s = NEGV;
                float mn = fmaxf(m, s);
                lsum = lsum * __expf(m - mn) + __expf(s - mn);
                m = mn;
                if (j == hd) sh = s;
            }
            float shv = (jg == (hd >> 4)) ? sh : 0.f;
            float mm = m, ll = lsum;
#pragma unroll
            for (int off = 1; off < 8; off <<= 1) {
                float m2 = __shfl_xor(mm, off);
                float l2 = __shfl_xor(ll, off);
                float mn = fmaxf(mm, m2);
                ll = ll * __expf(mm - mn) + l2 * __expf(m2 - mn);
                mm = mn;
                shv += __shfl_xor(shv, off);
            }
            if (jg == 0 && i >= 1 && !P.masks[b * Wn + i])
                acc += -(shv - (mm + __logf(ll)));
        }
        if (tid < 32) {
            int n = b * Wn + ic * 32 + tid;
            int r = P.dep_rels[n];
            if (r != 0 && r < Cn) {
                const float* sp = P.sc + (size_t)n * Cn;
                float mm = sp[0];
                for (int o = 1; o < Cn; ++o) mm = fmaxf(mm, sp[o]);
                float e = 0.f;
                for (int o = 0; o < Cn; ++o) e += __expf(sp[o] - mm);
                acc += -(sp[r] - (mm + __logf(e)));
            }
        }
        redf[tid] = acc;
        __syncthreads();
        for (int off = 128; off > 0; off >>= 1) {
            if (tid < off) redf[tid] += redf[tid + off];
            __syncthreads();
        }
        if (tid == 0) atomicAdd(P.out, redf[0]);
    }
}

extern "C" void kernel_launch(void* const* d_in, const int* in_sizes, int n_in,
                              void* d_out, int out_size, void* d_ws, size_t ws_size,
                              hipStream_t stream) {
    MegaP P;
    P.hid = (const float*)d_in[0];
    P.b2t = (const int*)d_in[1];
    P.heads = (const int*)d_in[2];
    P.dep_rels = (const int*)d_in[3];
    P.masks = (const unsigned char*)d_in[4];
    P.Wih_f = (const float*)d_in[6];
    P.Whh_f = (const float*)d_in[7];
    P.bih_f = (const float*)d_in[8];
    P.bhh_f = (const float*)d_in[9];
    P.Wih_b = (const float*)d_in[10];
    P.Whh_b = (const float*)d_in[11];
    P.bih_b = (const float*)d_in[12];
    P.bhh_b = (const float*)d_in[13];
    P.un_W1 = (const float*)d_in[14];
    P.un_b1 = (const float*)d_in[15];
    P.un_W2 = (const float*)d_in[16];
    P.un_b2 = (const float*)d_in[17];
    P.un_U  = (const float*)d_in[18];
    P.un_bias = (const float*)d_in[19];
    P.dr_W1 = (const float*)d_in[20];
    P.dr_b1 = (const float*)d_in[21];
    P.dr_W2 = (const float*)d_in[22];
    P.dr_b2 = (const float*)d_in[23];
    P.dr_U  = (const float*)d_in[24];
    P.dr_bias = (const float*)d_in[25];

    char* p = (char*)d_ws;
    P.tokg4 = (float*)p;  p += (size_t)8 * Bn * Sn * 80 * 4;
    P.xg = (float*)p;     p += (size_t)2 * Bn * Wn * 40 * 4;
    P.hs = (float*)p;     p += (size_t)2 * Bn * Wn * Hn * 4;
    P.hpad = (float*)p;   p += (size_t)4 * Bn * Wn * 32 * 4;
    P.sc = (float*)p;     p += (size_t)Bn * Wn * Cn * 4;
    P.out = (float*)d_out;

    void* args[] = { (void*)&P };
    hipLaunchCooperativeKernel((const void*)k_mega, dim3(512), dim3(256), args, 0, stream);
}

// Round 17
// 106.296 us; speedup vs baseline: 4.3148x; 4.3148x over previous
//
#include <hip/hip_runtime.h>

#define Bn 32
#define Wn 128
#define Sn 192
#define Dn 768
#define Hn 10
#define BHn 30
#define Cn 50
#define NEGV -1e30f

typedef _Float16 h2 __attribute__((ext_vector_type(2)));
typedef _Float16 h8 __attribute__((ext_vector_type(8)));
typedef __fp16 fp16x2 __attribute__((ext_vector_type(2)));
union H8u { h8 v; h2 p[4]; float4 f; };

__device__ __forceinline__ float fsig(float x) {
    return __builtin_amdgcn_rcpf(1.0f + __expf(-x));
}
__device__ __forceinline__ float ftanh(float x) {
    return 1.0f - 2.0f * __builtin_amdgcn_rcpf(1.0f + __expf(2.0f * x));
}
__device__ __forceinline__ float lane_bcast(float v, int srclane) {
    union { float f; int i; } u, w;
    u.f = v;
    w.i = __builtin_amdgcn_readlane(u.i, srclane);
    return w.f;
}
template <int Q>
__device__ __forceinline__ float quad_bcast(float v) {
    union { float f; int i; } u, w;
    u.f = v;
    w.i = __builtin_amdgcn_mov_dpp(u.i, (Q << 6) | (Q << 4) | (Q << 2) | Q, 0xf, 0xf, true);
    return w.f;
}
__device__ __forceinline__ h2 pk16(float a, float b) {
#if __has_builtin(__builtin_amdgcn_cvt_pkrtz)
    union { fp16x2 r; h2 h; } u;
    u.r = __builtin_amdgcn_cvt_pkrtz(a, b);
    return u.h;
#else
    h2 r; r[0] = (_Float16)a; r[1] = (_Float16)b; return r;
#endif
}
__device__ __forceinline__ float dot2f(h2 a, h2 b, float c) {
#if __has_builtin(__builtin_amdgcn_fdot2)
    return __builtin_amdgcn_fdot2(a, b, c, false);
#else
    return c + (float)a[0] * (float)b[0] + (float)a[1] * (float)b[1];
#endif
}

// ---------------- token projection v6 (round-14 verified): f16 LDS tiles + v_dot2 ----------------
#define XSTR2 52
__global__ __launch_bounds__(256) void k_tokproj(const float* __restrict__ hid,
                                                 const float* __restrict__ Wf,
                                                 const float* __restrict__ Wb,
                                                 float* __restrict__ tokg4,
                                                 float* __restrict__ out) {
    __shared__ h2 xl[64 * XSTR2];
    __shared__ h2 wl[80 * XSTR2];
    int tb = blockIdx.x >> 3;
    int kq = blockIdx.x & 7;
    int b = tb / 3;
    int s0 = (tb % 3) * 64;
    int k0 = kq * 96;
    int tid = threadIdx.x;
    if (blockIdx.x == 0 && tid == 0) out[0] = 0.f;

    for (int idx = tid; idx < 64 * 24; idx += 256) {
        int r = idx / 24, k4 = idx % 24;
        size_t rowbase = ((size_t)b * (Sn + 1) + (s0 + r + 1)) * Dn + k0 + 4 * k4;
        float4 v0 = *(const float4*)(hid + rowbase);
        float4 v1 = *(const float4*)(hid + (size_t)Bn * (Sn + 1) * Dn + rowbase);
        float4 v2 = *(const float4*)(hid + (size_t)2 * Bn * (Sn + 1) * Dn + rowbase);
        xl[r * XSTR2 + 2 * k4] = pk16(v0.x + v1.x + v2.x, v0.y + v1.y + v2.y);
        xl[r * XSTR2 + 2 * k4 + 1] = pk16(v0.z + v1.z + v2.z, v0.w + v1.w + v2.w);
    }
    for (int idx = tid; idx < 80 * 24; idx += 256) {
        int co = idx / 24, k4 = idx % 24;
        int dir = co / 40, off = co % 40;
        int j = off >> 2, g = off & 3;
        const float4 w = *(const float4*)((dir ? Wb : Wf) + (g * 10 + j) * Dn + k0 + 4 * k4);
        wl[co * XSTR2 + 2 * k4] = pk16(w.x, w.y);
        wl[co * XSTR2 + 2 * k4 + 1] = pk16(w.z, w.w);
    }
    __syncthreads();

    int tg = tid >> 4;
    int rg = tid & 15;
    float acc[4][5];
#pragma unroll
    for (int tt = 0; tt < 4; ++tt)
#pragma unroll
        for (int rr = 0; rr < 5; ++rr) acc[tt][rr] = 0.f;

    for (int kk = 0; kk < 12; ++kk) {
        H8u xv[4], wv[5];
#pragma unroll
        for (int tt = 0; tt < 4; ++tt)
            xv[tt].v = *(const h8*)(xl + (tg * 4 + tt) * XSTR2 + kk * 4);
#pragma unroll
        for (int rr = 0; rr < 5; ++rr)
            wv[rr].v = *(const h8*)(wl + (rg * 5 + rr) * XSTR2 + kk * 4);
#pragma unroll
        for (int tt = 0; tt < 4; ++tt)
#pragma unroll
            for (int rr = 0; rr < 5; ++rr) {
                float a = acc[tt][rr];
                a = dot2f(xv[tt].p[0], wv[rr].p[0], a);
                a = dot2f(xv[tt].p[1], wv[rr].p[1], a);
                a = dot2f(xv[tt].p[2], wv[rr].p[2], a);
                a = dot2f(xv[tt].p[3], wv[rr].p[3], a);
                acc[tt][rr] = a;
            }
    }
    size_t nbase = (size_t)kq * (Bn * Sn) + (size_t)b * Sn + s0;
#pragma unroll
    for (int tt = 0; tt < 4; ++tt) {
        size_t ob = (nbase + tg * 4 + tt) * 80 + rg * 5;
#pragma unroll
        for (int rr = 0; rr < 5; ++rr) tokg4[ob + rr] = acc[tt][rr];
    }
}

// ---------------- word segment-mean via direct b2t scan (round-14 verified) ----------------
__global__ __launch_bounds__(96) void k_wordmean(const float* __restrict__ tokg4,
                                                 const int* __restrict__ b2t,
                                                 const float* __restrict__ bih_f,
                                                 const float* __restrict__ bih_b,
                                                 float* __restrict__ xg) {
    const size_t NT80 = (size_t)Bn * Sn * 80;
    int bw = blockIdx.x;
    int b = bw >> 7, w = bw & 127;
    int tid = threadIdx.x;
    __shared__ int ws[Sn];
    ws[tid] = b2t[b * Sn + tid];
    ws[96 + tid] = b2t[b * Sn + 96 + tid];
    __syncthreads();
    if (tid >= 80) return;
    int dir = tid / 40, off = tid % 40;
    float acc = 0.f;
    int cnt = 0;
    for (int s = 0; s < Sn; ++s) {
        if (ws[s] == w) {
            ++cnt;
            size_t base = ((size_t)b * Sn + s) * 80 + tid;
#pragma unroll
            for (int p = 0; p < 8; ++p) acc += tokg4[base + p * NT80];
        }
    }
    float inv = 1.0f / (3.0f * (float)(cnt > 0 ? cnt : 1));
    int brow = (off & 3) * 10 + (off >> 2);
    float bias = (dir ? bih_b : bih_f)[brow];
    xg[((size_t)(dir * Bn + b) * Wn + w) * 40 + off] = acc * inv + bias;
}

// ---------------- fused LSTM scan + MLP heads: block = batch b (2 waves = fwd/bwd) ----------------
// Scan body identical to round-14 k_lstm (per-wave readlane/DPP); h kept in LDS; then MLP phase.
__global__ __launch_bounds__(128) void k_lstmmlp(const float* __restrict__ xg,
                                                 const float* __restrict__ Whh_f, const float* __restrict__ bhh_f,
                                                 const float* __restrict__ Whh_b, const float* __restrict__ bhh_b,
                                                 const float* __restrict__ uW1, const float* __restrict__ ub1,
                                                 const float* __restrict__ uW2, const float* __restrict__ ub2,
                                                 const float* __restrict__ dW1, const float* __restrict__ db1,
                                                 const float* __restrict__ dW2, const float* __restrict__ db2,
                                                 float* __restrict__ hpad) {
    __shared__ float hlds[Wn * 21]; // [t][dir*10+j], stride 21 -> conflict-free broadcast
    int b = blockIdx.x;
    int tid = threadIdx.x;
    {
        int dir = tid >> 6;        // wave 0 = fwd, wave 1 = bwd
        int lane = tid & 63;
        int seq = dir * Bn + b;
        int l = lane < 40 ? lane : 39;
        int j = l >> 2, G = l & 3;
        const float* Whh = dir ? Whh_b : Whh_f;
        const float* bhh = dir ? bhh_b : bhh_f;
        float wk[Hn];
#pragma unroll
        for (int k = 0; k < Hn; ++k) wk[k] = Whh[(G * Hn + j) * Hn + k];
        float bias = bhh[G * Hn + j];
        const float* xbase = xg + (size_t)seq * Wn * 40;
        bool st = (G == 0) && (lane < 40);
        float h = 0.f, c = 0.f;
        int dt = dir ? -1 : 1;
        int t = dir ? (Wn - 1) : 0;
        float xq[8];
#pragma unroll
        for (int q = 0; q < 7; ++q) xq[q] = xbase[(t + q * dt) * 40 + l];
#pragma unroll 8
        for (int step = 0; step < Wn; ++step) {
            float xv = xq[step & 7];
            xq[(step + 7) & 7] = xbase[(t + 7 * dt) * 40 + l];
            float hb[Hn];
#pragma unroll
            for (int k = 0; k < Hn; ++k) hb[k] = lane_bcast(h, 4 * k);
            float ga = xv, gb = bias;
#pragma unroll
            for (int k = 0; k < 5; ++k) ga += wk[k] * hb[k];
#pragma unroll
            for (int k = 5; k < Hn; ++k) gb += wk[k] * hb[k];
            float g = ga + gb;
            float gin = (G == 2) ? 2.f * g : g;
            float s = fsig(gin);
            float av = (G == 2) ? 2.f * s - 1.f : s;
            float ai = quad_bcast<0>(av);
            float af = quad_bcast<1>(av);
            float ag = quad_bcast<2>(av);
            float ao = quad_bcast<3>(av);
            c = af * c + ai * ag;
            h = ao * ftanh(c);
            if (st) hlds[t * 21 + dir * Hn + j] = h;
            t += dt;
        }
    }
    __syncthreads();
    // ---- MLP phase: thread = (which,k) output column, loops all 128 words ----
    if (tid < 124) {
        int which = tid / 31, k = tid % 31;
        size_t obase = ((size_t)which * Bn * Wn + (size_t)b * Wn) * 32;
        if (k == 30) {
            for (int t = 0; t < Wn; ++t) hpad[obase + (size_t)t * 32 + 30] = 1.0f;
        } else {
            const float* Wm;
            const float* bv;
            if (which == 0) { Wm = uW1; bv = ub1; }
            else if (which == 1) { Wm = uW2; bv = ub2; }
            else if (which == 2) { Wm = dW1; bv = db1; }
            else { Wm = dW2; bv = db2; }
            float wreg[20];
#pragma unroll
            for (int d = 0; d < 20; ++d) wreg[d] = Wm[d * BHn + k];
            float bias = bv[k];
            for (int t = 0; t < Wn; ++t) {
                float a = bias;
#pragma unroll
                for (int d = 0; d < 20; ++d) a += hlds[t * 21 + d] * wreg[d];
                hpad[obase + (size_t)t * 32 + k] = a > 0.f ? a : 0.f;
            }
        }
    } else {
        int which = tid - 124;
        size_t obase = ((size_t)which * Bn * Wn + (size_t)b * Wn) * 32;
        for (int t = 0; t < Wn; ++t) hpad[obase + (size_t)t * 32 + 31] = 0.f;
    }
}

// ---------------- deprel scores (round-14 verified) ----------------
__global__ __launch_bounds__(256) void k_drscore(const float* __restrict__ hpad,
                                                 const int* __restrict__ heads,
                                                 const float* __restrict__ U, const float* __restrict__ dbias,
                                                 float* __restrict__ sc) {
    int nc = blockIdx.x & 63;
    int oq = blockIdx.x >> 6;
    __shared__ float Ul[4][992];
    int tid = threadIdx.x;
    for (int idx = tid; idx < 4 * 992; idx += 256) {
        int o = idx / 992, r = idx - o * 992;
        int h = r >> 5, g = r & 31;
        int oo = oq * 4 + o; if (oo >= Cn) oo = Cn - 1;
        Ul[o][r] = (g < 31) ? U[(size_t)oo * 961 + h * 31 + g] : 0.f;
    }
    int w = tid >> 6, lane = tid & 63;
    int o = oq * 4 + w;
    int n = nc * 64 + lane;
    int b = n >> 7;
    int jh = heads[n];
    if (jh < 0 || jh >= Wn) jh = 0;
    const float* h1a = hpad + ((size_t)2 * Bn * Wn + n) * 32;
    const float* h2a = hpad + ((size_t)3 * Bn * Wn + b * Wn + jh) * 32;
    float h2r[32];
    {
        const float4* p = (const float4*)h2a;
#pragma unroll
        for (int q = 0; q < 8; ++q) {
            float4 v = p[q];
            h2r[4 * q + 0] = v.x; h2r[4 * q + 1] = v.y;
            h2r[4 * q + 2] = v.z; h2r[4 * q + 3] = v.w;
        }
    }
    float h1r[32];
    {
        const float4* p = (const float4*)h1a;
#pragma unroll
        for (int q = 0; q < 8; ++q) {
            float4 v = p[q];
            h1r[4 * q + 0] = v.x; h1r[4 * q + 1] = v.y;
            h1r[4 * q + 2] = v.z; h1r[4 * q + 3] = v.w;
        }
    }
    __syncthreads();
    const float* up = Ul[w];
    float acc = 0.f;
    for (int h = 0; h < 31; ++h) {
        float t = 0.f;
#pragma unroll
        for (int g = 0; g < 32; ++g) t += up[h * 32 + g] * h2r[g];
        acc += h1r[h] * t;
    }
    if (o < Cn) sc[(size_t)n * Cn + o] = acc + dbias[o];
}

// ---------------- fused losses (round-14 verified) ----------------
__global__ __launch_bounds__(256) void k_loss2(const float* __restrict__ hpad,
                                               const float* __restrict__ U0, const float* __restrict__ ubias,
                                               const float* __restrict__ sc,
                                               const int* __restrict__ heads,
                                               const unsigned char* __restrict__ masks,
                                               const int* __restrict__ dep_rels,
                                               float* __restrict__ out) {
    int b = blockIdx.x >> 2;
    int ic = blockIdx.x & 3;
    int tid = threadIdx.x;
    __shared__ float h2s[128 * 36];
    __shared__ float tg[32 * 36];
    __shared__ float U0l[992];
    __shared__ float red[256];
    const float* h1a = hpad + (size_t)b * Wn * 32;
    const float* h2a = hpad + ((size_t)Bn * Wn + b * Wn) * 32;
    for (int idx = tid; idx < 128 * 32; idx += 256)
        h2s[(idx >> 5) * 36 + (idx & 31)] = h2a[idx];
    for (int idx = tid; idx < 992; idx += 256) {
        int g = idx & 31;
        U0l[idx] = (g < 31) ? U0[(idx >> 5) * 31 + g] : 0.f;
    }
    __syncthreads();
    {
        int l = tid & 31, ig = tid >> 5;
        float ur[31];
#pragma unroll
        for (int h = 0; h < 31; ++h) ur[h] = U0l[h * 32 + l];
        for (int ii = 0; ii < 4; ++ii) {
            int il = ig * 4 + ii;
            int i = ic * 32 + il;
            const float4* hp = (const float4*)(h1a + (size_t)i * 32);
            float hr[32];
#pragma unroll
            for (int q = 0; q < 8; ++q) {
                float4 v = hp[q];
                hr[4 * q] = v.x; hr[4 * q + 1] = v.y; hr[4 * q + 2] = v.z; hr[4 * q + 3] = v.w;
            }
            float a = 0.f;
#pragma unroll
            for (int h = 0; h < 31; ++h) a += hr[h] * ur[h];
            tg[il * 36 + l] = a;
        }
    }
    __syncthreads();
    float acc = 0.f;
    {
        int jg = tid & 7, il = tid >> 3;
        int i = ic * 32 + il;
        float ub = ubias[0];
        float4 tq[8];
        const float4* tp = (const float4*)(tg + il * 36);
#pragma unroll
        for (int q = 0; q < 8; ++q) tq[q] = tp[q];
        float m = -3e38f, lsum = 0.f, sh = 0.f;
        int hd = heads[b * Wn + i];
        for (int jj = 0; jj < 16; ++jj) {
            int j = jg * 16 + ((jj + jg) & 15);
            const float4* h2p = (const float4*)(h2s + j * 36);
            float s = ub;
#pragma unroll
            for (int q = 0; q < 8; ++q) {
                float4 hq = h2p[q];
                s += tq[q].x * hq.x + tq[q].y * hq.y + tq[q].z * hq.z + tq[q].w * hq.w;
            }
            if (j == i) s = NEGV;
            float mn = fmaxf(m, s);
            lsum = lsum * __expf(m - mn) + __expf(s - mn);
            m = mn;
            if (j == hd) sh = s;
        }
        float shv = (jg == (hd >> 4)) ? sh : 0.f;
        float mm = m, ll = lsum;
#pragma unroll
        for (int off = 1; off < 8; off <<= 1) {
            float m2 = __shfl_xor(mm, off);
            float l2 = __shfl_xor(ll, off);
            float mn = fmaxf(mm, m2);
            ll = ll * __expf(mm - mn) + l2 * __expf(m2 - mn);
            mm = mn;
            shv += __shfl_xor(shv, off);
        }
        if (jg == 0 && i >= 1 && !masks[b * Wn + i])
            acc += -(shv - (mm + __logf(ll)));
    }
    if (tid < 32) {
        int n = b * Wn + ic * 32 + tid;
        int r = dep_rels[n];
        if (r != 0 && r < Cn) {
            const float* sp = sc + (size_t)n * Cn;
            float mm = sp[0];
            for (int o = 1; o < Cn; ++o) mm = fmaxf(mm, sp[o]);
            float e = 0.f;
            for (int o = 0; o < Cn; ++o) e += __expf(sp[o] - mm);
            acc += -(sp[r] - (mm + __logf(e)));
        }
    }
    red[tid] = acc;
    __syncthreads();
    for (int off = 128; off > 0; off >>= 1) {
        if (tid < off) red[tid] += red[tid + off];
        __syncthreads();
    }
    if (tid == 0) atomicAdd(out, red[0]);
}

extern "C" void kernel_launch(void* const* d_in, const int* in_sizes, int n_in,
                              void* d_out, int out_size, void* d_ws, size_t ws_size,
                              hipStream_t stream) {
    const float* hiddens = (const float*)d_in[0];
    const int* b2t = (const int*)d_in[1];
    const int* heads = (const int*)d_in[2];
    const int* dep_rels = (const int*)d_in[3];
    const unsigned char* masks = (const unsigned char*)d_in[4];
    const float* Wih_f = (const float*)d_in[6];
    const float* Whh_f = (const float*)d_in[7];
    const float* bih_f = (const float*)d_in[8];
    const float* bhh_f = (const float*)d_in[9];
    const float* Wih_b = (const float*)d_in[10];
    const float* Whh_b = (const float*)d_in[11];
    const float* bih_b = (const float*)d_in[12];
    const float* bhh_b = (const float*)d_in[13];
    const float* un_W1 = (const float*)d_in[14];
    const float* un_b1 = (const float*)d_in[15];
    const float* un_W2 = (const float*)d_in[16];
    const float* un_b2 = (const float*)d_in[17];
    const float* un_U  = (const float*)d_in[18];
    const float* un_bias = (const float*)d_in[19];
    const float* dr_W1 = (const float*)d_in[20];
    const float* dr_b1 = (const float*)d_in[21];
    const float* dr_W2 = (const float*)d_in[22];
    const float* dr_b2 = (const float*)d_in[23];
    const float* dr_U  = (const float*)d_in[24];
    const float* dr_bias = (const float*)d_in[25];

    char* p = (char*)d_ws;
    float* tokg4 = (float*)p;     p += (size_t)8 * Bn * Sn * 80 * 4;
    float* xg = (float*)p;        p += (size_t)2 * Bn * Wn * 40 * 4;
    float* hpad = (float*)p;      p += (size_t)4 * Bn * Wn * 32 * 4;
    float* sc = (float*)p;        p += (size_t)Bn * Wn * Cn * 4;

    float* out = (float*)d_out;

    k_tokproj<<<96 * 8, 256, 0, stream>>>(hiddens, Wih_f, Wih_b, tokg4, out);
    k_wordmean<<<Bn * Wn, 96, 0, stream>>>(tokg4, b2t, bih_f, bih_b, xg);
    k_lstmmlp<<<Bn, 128, 0, stream>>>(xg, Whh_f, bhh_f, Whh_b, bhh_b,
                                      un_W1, un_b1, un_W2, un_b2,
                                      dr_W1, dr_b1, dr_W2, dr_b2, hpad);
    k_drscore<<<13 * 64, 256, 0, stream>>>(hpad, heads, dr_U, dr_bias, sc);
    k_loss2<<<Bn * 4, 256, 0, stream>>>(hpad, un_U, un_bias, sc, heads, masks, dep_rels, out);
}

// Round 18
// 94.617 us; speedup vs baseline: 4.8474x; 1.1234x over previous
//
#include <hip/hip_runtime.h>

#define Bn 32
#define Wn 128
#define Sn 192
#define Dn 768
#define Hn 10
#define BHn 30
#define Cn 50
#define NEGV -1e30f

typedef _Float16 h2 __attribute__((ext_vector_type(2)));
typedef _Float16 h8 __attribute__((ext_vector_type(8)));
typedef __fp16 fp16x2 __attribute__((ext_vector_type(2)));
union H8u { h8 v; h2 p[4]; float4 f; };

__device__ __forceinline__ float fsig(float x) {
    return __builtin_amdgcn_rcpf(1.0f + __expf(-x));
}
__device__ __forceinline__ float ftanh(float x) {
    return 1.0f - 2.0f * __builtin_amdgcn_rcpf(1.0f + __expf(2.0f * x));
}
__device__ __forceinline__ float lane_bcast(float v, int srclane) {
    union { float f; int i; } u, w;
    u.f = v;
    w.i = __builtin_amdgcn_readlane(u.i, srclane);
    return w.f;
}
template <int Q>
__device__ __forceinline__ float quad_bcast(float v) {
    union { float f; int i; } u, w;
    u.f = v;
    w.i = __builtin_amdgcn_mov_dpp(u.i, (Q << 6) | (Q << 4) | (Q << 2) | Q, 0xf, 0xf, true);
    return w.f;
}
__device__ __forceinline__ h2 pk16(float a, float b) {
#if __has_builtin(__builtin_amdgcn_cvt_pkrtz)
    union { fp16x2 r; h2 h; } u;
    u.r = __builtin_amdgcn_cvt_pkrtz(a, b);
    return u.h;
#else
    h2 r; r[0] = (_Float16)a; r[1] = (_Float16)b; return r;
#endif
}
__device__ __forceinline__ float dot2f(h2 a, h2 b, float c) {
#if __has_builtin(__builtin_amdgcn_fdot2)
    return __builtin_amdgcn_fdot2(a, b, c, false);
#else
    return c + (float)a[0] * (float)b[0] + (float)a[1] * (float)b[1];
#endif
}

// ---------------- token projection v6: f16 LDS tiles + v_dot2, 30KB LDS ----------------
// block = 64 tokens x 80 rows x K-eighth(96); 256 threads; thread = 4 tok x 5 rows.
// tokg4[kq][n][co] partial (fp32), co = dir*40 + j*4 + gate.
#define XSTR2 52   // h2 units per row (48 data + 4 pad) -> 208B row stride
__global__ __launch_bounds__(256) void k_tokproj(const float* __restrict__ hid,
                                                 const float* __restrict__ Wf,
                                                 const float* __restrict__ Wb,
                                                 float* __restrict__ tokg4,
                                                 float* __restrict__ out) {
    __shared__ h2 xl[64 * XSTR2];  // 13.3KB
    __shared__ h2 wl[80 * XSTR2];  // 16.6KB
    int tb = blockIdx.x >> 3;
    int kq = blockIdx.x & 7;
    int b = tb / 3;
    int s0 = (tb % 3) * 64;
    int k0 = kq * 96;
    int tid = threadIdx.x;
    if (blockIdx.x == 0 && tid == 0) out[0] = 0.f; // zero loss accumulator (k_loss2 runs later)

    // stage x: sum of 3 layers -> f16, 64 tokens x 24 float4-of-source
    for (int idx = tid; idx < 64 * 24; idx += 256) {
        int r = idx / 24, k4 = idx % 24;
        size_t rowbase = ((size_t)b * (Sn + 1) + (s0 + r + 1)) * Dn + k0 + 4 * k4;
        float4 v0 = *(const float4*)(hid + rowbase);
        float4 v1 = *(const float4*)(hid + (size_t)Bn * (Sn + 1) * Dn + rowbase);
        float4 v2 = *(const float4*)(hid + (size_t)2 * Bn * (Sn + 1) * Dn + rowbase);
        h2 a = pk16(v0.x + v1.x + v2.x, v0.y + v1.y + v2.y);
        h2 bb = pk16(v0.z + v1.z + v2.z, v0.w + v1.w + v2.w);
        xl[r * XSTR2 + 2 * k4] = a;
        xl[r * XSTR2 + 2 * k4 + 1] = bb;
    }
    // stage W: full 96-k chunk -> f16
    for (int idx = tid; idx < 80 * 24; idx += 256) {
        int co = idx / 24, k4 = idx % 24;
        int dir = co / 40, off = co % 40;
        int j = off >> 2, g = off & 3;
        const float4 w = *(const float4*)((dir ? Wb : Wf) + (g * 10 + j) * Dn + k0 + 4 * k4);
        wl[co * XSTR2 + 2 * k4] = pk16(w.x, w.y);
        wl[co * XSTR2 + 2 * k4 + 1] = pk16(w.z, w.w);
    }
    __syncthreads();

    int tg = tid >> 4;  // 0..15 -> tokens tg*4..tg*4+3
    int rg = tid & 15;  // 0..15 -> co-rows rg*5..rg*5+4
    float acc[4][5];
#pragma unroll
    for (int tt = 0; tt < 4; ++tt)
#pragma unroll
        for (int rr = 0; rr < 5; ++rr) acc[tt][rr] = 0.f;

    for (int kk = 0; kk < 12; ++kk) { // 12 x 8-half steps = 96 k
        H8u xv[4], wv[5];
#pragma unroll
        for (int tt = 0; tt < 4; ++tt)
            xv[tt].v = *(const h8*)(xl + (tg * 4 + tt) * XSTR2 + kk * 4);
#pragma unroll
        for (int rr = 0; rr < 5; ++rr)
            wv[rr].v = *(const h8*)(wl + (rg * 5 + rr) * XSTR2 + kk * 4);
#pragma unroll
        for (int tt = 0; tt < 4; ++tt)
#pragma unroll
            for (int rr = 0; rr < 5; ++rr) {
                float a = acc[tt][rr];
                a = dot2f(xv[tt].p[0], wv[rr].p[0], a);
                a = dot2f(xv[tt].p[1], wv[rr].p[1], a);
                a = dot2f(xv[tt].p[2], wv[rr].p[2], a);
                a = dot2f(xv[tt].p[3], wv[rr].p[3], a);
                acc[tt][rr] = a;
            }
    }
    size_t nbase = (size_t)kq * (Bn * Sn) + (size_t)b * Sn + s0;
#pragma unroll
    for (int tt = 0; tt < 4; ++tt) {
        size_t ob = (nbase + tg * 4 + tt) * 80 + rg * 5;
#pragma unroll
        for (int rr = 0; rr < 5; ++rr) tokg4[ob + rr] = acc[tt][rr];
    }
}

// ---------------- word segment-mean via direct b2t scan (wave-uniform branch) ----------------
__global__ __launch_bounds__(96) void k_wordmean(const float* __restrict__ tokg4,
                                                 const int* __restrict__ b2t,
                                                 const float* __restrict__ bih_f,
                                                 const float* __restrict__ bih_b,
                                                 float* __restrict__ xg) {
    const size_t NT80 = (size_t)Bn * Sn * 80;
    int bw = blockIdx.x; // b*Wn + w
    int b = bw >> 7, w = bw & 127;
    int tid = threadIdx.x;
    __shared__ int ws[Sn];
    ws[tid] = b2t[b * Sn + tid];
    ws[96 + tid] = b2t[b * Sn + 96 + tid];
    __syncthreads();
    if (tid >= 80) return;
    int dir = tid / 40, off = tid % 40;
    float acc = 0.f;
    int cnt = 0;
    for (int s = 0; s < Sn; ++s) {
        if (ws[s] == w) { // uniform across lanes
            ++cnt;
            size_t base = ((size_t)b * Sn + s) * 80 + tid;
#pragma unroll
            for (int p = 0; p < 8; ++p) acc += tokg4[base + p * NT80];
        }
    }
    float inv = 1.0f / (3.0f * (float)(cnt > 0 ? cnt : 1));
    int brow = (off & 3) * 10 + (off >> 2); // gate*10 + j
    float bias = (dir ? bih_b : bih_f)[brow];
    xg[((size_t)(dir * Bn + b) * Wn + w) * 40 + off] = acc * inv + bias;
}

// ---------------- LSTM scan: 1 seq/wave, readlane h-broadcast, DPP gate combine ----------------
__global__ __launch_bounds__(64) void k_lstm(const float* __restrict__ xg,
                                             const float* __restrict__ Whh_f, const float* __restrict__ bhh_f,
                                             const float* __restrict__ Whh_b, const float* __restrict__ bhh_b,
                                             float* __restrict__ hs) {
    int lane = threadIdx.x;
    int seq = blockIdx.x;      // 0..63
    int dir = seq >> 5;
    int l = lane < 40 ? lane : 39;
    int j = l >> 2, G = l & 3;

    const float* Whh = dir ? Whh_b : Whh_f;
    const float* bhh = dir ? bhh_b : bhh_f;
    float wk[Hn];
#pragma unroll
    for (int k = 0; k < Hn; ++k) wk[k] = Whh[(G * Hn + j) * Hn + k];
    float bias = bhh[G * Hn + j];

    const float* xbase = xg + (size_t)seq * Wn * 40; // layout [t][j*4+gate]
    float* hbase = hs + (size_t)seq * Wn * Hn;
    bool st = (G == 0) && (lane < 40);

    float h = 0.f, c = 0.f;
    int dt = dir ? -1 : 1;
    int t = dir ? (Wn - 1) : 0;
    float xq[8];
#pragma unroll
    for (int q = 0; q < 7; ++q) xq[q] = xbase[(t + q * dt) * 40 + l];

#pragma unroll 8
    for (int step = 0; step < Wn; ++step) {
        float xv = xq[step & 7];
        xq[(step + 7) & 7] = xbase[(t + 7 * dt) * 40 + l]; // prefetch 7 ahead
        float hb[Hn];
#pragma unroll
        for (int k = 0; k < Hn; ++k) hb[k] = lane_bcast(h, 4 * k);
        float ga = xv, gb = bias;
#pragma unroll
        for (int k = 0; k < 5; ++k) ga += wk[k] * hb[k];
#pragma unroll
        for (int k = 5; k < Hn; ++k) gb += wk[k] * hb[k];
        float g = ga + gb;
        float gin = (G == 2) ? 2.f * g : g;
        float s = fsig(gin);
        float av = (G == 2) ? 2.f * s - 1.f : s;
        float ai = quad_bcast<0>(av);
        float af = quad_bcast<1>(av);
        float ag = quad_bcast<2>(av);
        float ao = quad_bcast<3>(av);
        c = af * c + ai * ag;
        h = ao * ftanh(c);
        if (st) hbase[t * Hn + j] = h;
        t += dt;
    }
}

// ---------------- MLP heads -> padded hpad[which][n][32] ----------------
__global__ __launch_bounds__(128) void k_mlp(const float* __restrict__ hs,
                                             const float* __restrict__ uW1, const float* __restrict__ ub1,
                                             const float* __restrict__ uW2, const float* __restrict__ ub2,
                                             const float* __restrict__ dW1, const float* __restrict__ db1,
                                             const float* __restrict__ dW2, const float* __restrict__ db2,
                                             float* __restrict__ hpad) {
    int bt = blockIdx.x; // b*Wn + t
    int b = bt / Wn, t = bt % Wn;
    __shared__ float x[20];
    int tid = threadIdx.x;
    if (tid < 20) {
        x[tid] = (tid < Hn) ? hs[((size_t)(0 * Bn + b) * Wn + t) * Hn + tid]
                            : hs[((size_t)(1 * Bn + b) * Wn + t) * Hn + (tid - Hn)];
    }
    __syncthreads();
    if (tid >= 124) { // pads for all 4 heads
        hpad[((size_t)(tid - 124) * Bn * Wn + bt) * 32 + 31] = 0.f;
        return;
    }
    int which = tid / 31, k = tid % 31;
    float v;
    if (k == 30) {
        v = 1.0f;
    } else {
        const float* Wm;
        const float* bv;
        if (which == 0) { Wm = uW1; bv = ub1; }
        else if (which == 1) { Wm = uW2; bv = ub2; }
        else if (which == 2) { Wm = dW1; bv = db1; }
        else { Wm = dW2; bv = db2; }
        float a = bv[k];
#pragma unroll
        for (int d = 0; d < 20; ++d) a += x[d] * Wm[d * BHn + k];
        v = a > 0.f ? a : 0.f;
    }
    hpad[((size_t)which * Bn * Wn + bt) * 32 + k] = v;
}

// ---------------- deprel scores: thread=(n,o), inline head-gather, U broadcast from LDS ----------------
__global__ __launch_bounds__(256) void k_drscore(const float* __restrict__ hpad,
                                                 const int* __restrict__ heads,
                                                 const float* __restrict__ U, const float* __restrict__ dbias,
                                                 float* __restrict__ sc) {
    int nc = blockIdx.x & 63;
    int oq = blockIdx.x >> 6; // 0..12
    __shared__ float Ul[4][992]; // row stride 32 per h (aligned b128)
    int tid = threadIdx.x;
    for (int idx = tid; idx < 4 * 992; idx += 256) {
        int o = idx / 992, r = idx - o * 992;
        int h = r >> 5, g = r & 31;
        int oo = oq * 4 + o; if (oo >= Cn) oo = Cn - 1;
        Ul[o][r] = (g < 31) ? U[(size_t)oo * 961 + h * 31 + g] : 0.f;
    }
    int w = tid >> 6, lane = tid & 63;
    int o = oq * 4 + w;
    int n = nc * 64 + lane;
    int b = n >> 7;
    int jh = heads[n];
    if (jh < 0 || jh >= Wn) jh = 0;
    const float* h1a = hpad + ((size_t)2 * Bn * Wn + n) * 32;
    const float* h2a = hpad + ((size_t)3 * Bn * Wn + b * Wn + jh) * 32;
    float h2r[32];
    {
        const float4* p = (const float4*)h2a;
#pragma unroll
        for (int q = 0; q < 8; ++q) {
            float4 v = p[q];
            h2r[4 * q + 0] = v.x; h2r[4 * q + 1] = v.y;
            h2r[4 * q + 2] = v.z; h2r[4 * q + 3] = v.w;
        }
    }
    float h1r[32];
    {
        const float4* p = (const float4*)h1a;
#pragma unroll
        for (int q = 0; q < 8; ++q) {
            float4 v = p[q];
            h1r[4 * q + 0] = v.x; h1r[4 * q + 1] = v.y;
            h1r[4 * q + 2] = v.z; h1r[4 * q + 3] = v.w;
        }
    }
    __syncthreads();
    const float* up = Ul[w];
    float acc = 0.f;
    for (int h = 0; h < 31; ++h) {
        float t = 0.f;
#pragma unroll
        for (int g = 0; g < 32; ++g) t += up[h * 32 + g] * h2r[g];
        acc += h1r[h] * t;
    }
    if (o < Cn) sc[(size_t)n * Cn + o] = acc + dbias[o];
}

// ---------------- fused losses: block = (b, i-chunk of 32); 128 blocks ----------------
__global__ __launch_bounds__(256) void k_loss2(const float* __restrict__ hpad,
                                               const float* __restrict__ U0, const float* __restrict__ ubias,
                                               const float* __restrict__ sc,
                                               const int* __restrict__ heads,
                                               const unsigned char* __restrict__ masks,
                                               const int* __restrict__ dep_rels,
                                               float* __restrict__ out) {
    int b = blockIdx.x >> 2;
    int ic = blockIdx.x & 3;
    int tid = threadIdx.x;
    __shared__ float h2s[128 * 36];
    __shared__ float tg[32 * 36];
    __shared__ float U0l[992];
    __shared__ float red[256];
    const float* h1a = hpad + (size_t)b * Wn * 32;                 // un h1 (padded)
    const float* h2a = hpad + ((size_t)Bn * Wn + b * Wn) * 32;     // un h2 (padded)
    for (int idx = tid; idx < 128 * 32; idx += 256)
        h2s[(idx >> 5) * 36 + (idx & 31)] = h2a[idx];
    for (int idx = tid; idx < 992; idx += 256) {
        int g = idx & 31;
        U0l[idx] = (g < 31) ? U0[(idx >> 5) * 31 + g] : 0.f;
    }
    __syncthreads();
    // tg[il][l] = sum_h h1[ic*32+il][h] * U0[h][l]
    {
        int l = tid & 31, ig = tid >> 5; // ig 0..7 -> 4 local rows each
        float ur[31];
#pragma unroll
        for (int h = 0; h < 31; ++h) ur[h] = U0l[h * 32 + l];
        for (int ii = 0; ii < 4; ++ii) {
            int il = ig * 4 + ii;
            int i = ic * 32 + il;
            const float4* hp = (const float4*)(h1a + (size_t)i * 32);
            float hr[32];
#pragma unroll
            for (int q = 0; q < 8; ++q) {
                float4 v = hp[q];
                hr[4 * q] = v.x; hr[4 * q + 1] = v.y; hr[4 * q + 2] = v.z; hr[4 * q + 3] = v.w;
            }
            float a = 0.f;
#pragma unroll
            for (int h = 0; h < 31; ++h) a += hr[h] * ur[h];
            tg[il * 36 + l] = a;
        }
    }
    __syncthreads();
    float acc = 0.f;
    {
        int jg = tid & 7, il = tid >> 3; // il 0..31, one i-row per thread
        int i = ic * 32 + il;
        float ub = ubias[0];
        float4 tq[8];
        const float4* tp = (const float4*)(tg + il * 36);
#pragma unroll
        for (int q = 0; q < 8; ++q) tq[q] = tp[q];
        float m = -3e38f, lsum = 0.f, sh = 0.f;
        int hd = heads[b * Wn + i];
        for (int jj = 0; jj < 16; ++jj) {
            int j = jg * 16 + ((jj + jg) & 15); // rotated: 8 jg-lanes hit 8 distinct bank groups
            const float4* h2p = (const float4*)(h2s + j * 36);
            float s = ub;
#pragma unroll
            for (int q = 0; q < 8; ++q) {
                float4 hq = h2p[q];
                s += tq[q].x * hq.x + tq[q].y * hq.y + tq[q].z * hq.z + tq[q].w * hq.w;
            }
            if (j == i) s = NEGV;
            float mn = fmaxf(m, s);
            lsum = lsum * __expf(m - mn) + __expf(s - mn);
            m = mn;
            if (j == hd) sh = s;
        }
        float shv = (jg == (hd >> 4)) ? sh : 0.f;
        float mm = m, ll = lsum;
#pragma unroll
        for (int off = 1; off < 8; off <<= 1) {
            float m2 = __shfl_xor(mm, off);
            float l2 = __shfl_xor(ll, off);
            float mn = fmaxf(mm, m2);
            ll = ll * __expf(mm - mn) + l2 * __expf(m2 - mn);
            mm = mn;
            shv += __shfl_xor(shv, off);
        }
        if (jg == 0 && i >= 1 && !masks[b * Wn + i])
            acc += -(shv - (mm + __logf(ll)));
    }
    // deprel CE for this block's 32 rows
    if (tid < 32) {
        int n = b * Wn + ic * 32 + tid;
        int r = dep_rels[n];
        if (r != 0 && r < Cn) {
            const float* sp = sc + (size_t)n * Cn;
            float mm = sp[0];
            for (int o = 1; o < Cn; ++o) mm = fmaxf(mm, sp[o]);
            float e = 0.f;
            for (int o = 0; o < Cn; ++o) e += __expf(sp[o] - mm);
            acc += -(sp[r] - (mm + __logf(e)));
        }
    }
    red[tid] = acc;
    __syncthreads();
    for (int off = 128; off > 0; off >>= 1) {
        if (tid < off) red[tid] += red[tid + off];
        __syncthreads();
    }
    if (tid == 0) atomicAdd(out, red[0]);
}

extern "C" void kernel_launch(void* const* d_in, const int* in_sizes, int n_in,
                              void* d_out, int out_size, void* d_ws, size_t ws_size,
                              hipStream_t stream) {
    const float* hiddens = (const float*)d_in[0];
    const int* b2t = (const int*)d_in[1];
    const int* heads = (const int*)d_in[2];
    const int* dep_rels = (const int*)d_in[3];
    const unsigned char* masks = (const unsigned char*)d_in[4];
    const float* Wih_f = (const float*)d_in[6];
    const float* Whh_f = (const float*)d_in[7];
    const float* bih_f = (const float*)d_in[8];
    const float* bhh_f = (const float*)d_in[9];
    const float* Wih_b = (const float*)d_in[10];
    const float* Whh_b = (const float*)d_in[11];
    const float* bih_b = (const float*)d_in[12];
    const float* bhh_b = (const float*)d_in[13];
    const float* un_W1 = (const float*)d_in[14];
    const float* un_b1 = (const float*)d_in[15];
    const float* un_W2 = (const float*)d_in[16];
    const float* un_b2 = (const float*)d_in[17];
    const float* un_U  = (const float*)d_in[18];
    const float* un_bias = (const float*)d_in[19];
    const float* dr_W1 = (const float*)d_in[20];
    const float* dr_b1 = (const float*)d_in[21];
    const float* dr_W2 = (const float*)d_in[22];
    const float* dr_b2 = (const float*)d_in[23];
    const float* dr_U  = (const float*)d_in[24];
    const float* dr_bias = (const float*)d_in[25];

    char* p = (char*)d_ws;
    float* tokg4 = (float*)p;     p += (size_t)8 * Bn * Sn * 80 * 4;
    float* xg = (float*)p;        p += (size_t)2 * Bn * Wn * 40 * 4;
    float* hs = (float*)p;        p += (size_t)2 * Bn * Wn * Hn * 4;
    float* hpad = (float*)p;      p += (size_t)4 * Bn * Wn * 32 * 4;
    float* sc = (float*)p;        p += (size_t)Bn * Wn * Cn * 4;

    float* out = (float*)d_out;

    k_tokproj<<<96 * 8, 256, 0, stream>>>(hiddens, Wih_f, Wih_b, tokg4, out);
    k_wordmean<<<Bn * Wn, 96, 0, stream>>>(tokg4, b2t, bih_f, bih_b, xg);
    k_lstm<<<64, 64, 0, stream>>>(xg, Whh_f, bhh_f, Whh_b, bhh_b, hs);
    k_mlp<<<Bn * Wn, 128, 0, stream>>>(hs, un_W1, un_b1, un_W2, un_b2,
                                       dr_W1, dr_b1, dr_W2, dr_b2, hpad);
    k_drscore<<<13 * 64, 256, 0, stream>>>(hpad, heads, dr_U, dr_bias, sc);
    k_loss2<<<Bn * 4, 256, 0, stream>>>(hpad, un_U, un_bias, sc, heads, masks, dep_rels, out);
}